// Round 1
// baseline (938.175 us; speedup 1.0000x reference)
//
#include <hip/hip_runtime.h>

// ---------------------------------------------------------------------------
// Shifted-window attention (Swin), MI355X bf16-MFMA implementation.
// B=32, H=W=56, C=384, nh=12, dh=32, ws=7 (T=49), shift=3, windows=2048.
// Pipeline: zpad -> qkv gemm (gather fused) -> per-(win,head) attention ->
//           proj gemm (scatter fused).
// ---------------------------------------------------------------------------

typedef __bf16 bf16;
typedef __bf16 bf16x8 __attribute__((ext_vector_type(8)));
typedef float f32x4 __attribute__((ext_vector_type(4)));

#define NWIN   2048        // 32 * 64 windows
#define WHN    24576       // NWIN * 12 heads
#define GTOK   100352      // NWIN * 49 tokens
#define QKV_SCALE 0.17677669529663687f

// workspace offsets (bytes)
#define QB_OFF 0u
#define KB_OFF 77070336u
#define VT_OFF 154140672u
#define AB_OFF 254803968u
// total needed: 331,874,304 bytes

__device__ inline bf16x8 bzero8() {
  bf16x8 z;
#pragma unroll
  for (int i = 0; i < 8; ++i) z[i] = (bf16)0.0f;
  return z;
}

// --------------------------------------------------------------------------
// zero the token-padding (t=49..63) of vT[WHN][32][64]
// --------------------------------------------------------------------------
__global__ void k_zpad(bf16* __restrict__ vtb) {
  int idx = blockIdx.x * 256 + threadIdx.x;   // row index over WHN*32
  if (idx < WHN * 32) {
    bf16* p = vtb + (size_t)idx * 64 + 49;
#pragma unroll
    for (int i = 0; i < 15; ++i) p[i] = (bf16)0.0f;
  }
}

// --------------------------------------------------------------------------
// QKV: gather (roll -3 + window partition) + GEMM  [GTOK x 1152, K=384]
// grid (1568, 18), block 256. 64x64 tile, K-step 32.
// --------------------------------------------------------------------------
__global__ __launch_bounds__(256) void k_qkv(
    const float* __restrict__ x, const float* __restrict__ wqkv,
    const float* __restrict__ bqkv, bf16* __restrict__ qb,
    bf16* __restrict__ kb, bf16* __restrict__ vtb) {
  __shared__ __align__(16) bf16 As[64][40];
  __shared__ __align__(16) bf16 Bs[64][40];

  int tid = threadIdx.x;
  int m0 = blockIdx.x * 64;
  int n0 = blockIdx.y * 64;
  int which = blockIdx.y / 6;          // 0:q 1:k 2:v (uniform per block)

  int lrow = tid >> 2;                 // 0..63
  int lcol = (tid & 3) * 8;            // 0,8,16,24

  // source row for the A (activation) tile: token g -> rolled pixel
  int g = m0 + lrow;
  int w = g / 49, t = g - w * 49;
  int b = w >> 6, wi = w & 63;
  int wy = wi >> 3, wx = wi & 7;
  int ty = t / 7, tx = t - ty * 7;
  int sy = wy * 7 + ty + 3; if (sy >= 56) sy -= 56;
  int sx = wx * 7 + tx + 3; if (sx >= 56) sx -= 56;
  const float* arow = x + (size_t)(((b * 56 + sy) * 56 + sx)) * 384;
  const float* brow = wqkv + (size_t)(n0 + lrow) * 384;

  int wv = tid >> 6, lane = tid & 63;
  int l16 = lane & 15, q4 = lane >> 4;

  f32x4 acc[4];
#pragma unroll
  for (int c = 0; c < 4; ++c) acc[c] = (f32x4){0.f, 0.f, 0.f, 0.f};

  for (int k0 = 0; k0 < 384; k0 += 32) {
    float4 a0 = *(const float4*)(arow + k0 + lcol);
    float4 a1 = *(const float4*)(arow + k0 + lcol + 4);
    float4 b0 = *(const float4*)(brow + k0 + lcol);
    float4 b1 = *(const float4*)(brow + k0 + lcol + 4);
    __syncthreads();   // previous iteration's frag reads done
    bf16x8 av, bv;
    av[0] = (bf16)a0.x; av[1] = (bf16)a0.y; av[2] = (bf16)a0.z; av[3] = (bf16)a0.w;
    av[4] = (bf16)a1.x; av[5] = (bf16)a1.y; av[6] = (bf16)a1.z; av[7] = (bf16)a1.w;
    bv[0] = (bf16)b0.x; bv[1] = (bf16)b0.y; bv[2] = (bf16)b0.z; bv[3] = (bf16)b0.w;
    bv[4] = (bf16)b1.x; bv[5] = (bf16)b1.y; bv[6] = (bf16)b1.z; bv[7] = (bf16)b1.w;
    *(bf16x8*)&As[lrow][lcol] = av;
    *(bf16x8*)&Bs[lrow][lcol] = bv;
    __syncthreads();
    bf16x8 af = *(const bf16x8*)&As[wv * 16 + l16][q4 * 8];
#pragma unroll
    for (int c = 0; c < 4; ++c) {
      bf16x8 bfm = *(const bf16x8*)&Bs[c * 16 + l16][q4 * 8];
      acc[c] = __builtin_amdgcn_mfma_f32_16x16x32_bf16(af, bfm, acc[c], 0, 0, 0);
    }
  }

  // epilogue: bias, (scale for q), scatter into q/k/vT bf16 buffers
  float biasv[4]; int hh[4], dd[4];
#pragma unroll
  for (int c = 0; c < 4; ++c) {
    int n = n0 + c * 16 + l16;
    biasv[c] = bqkv[n];
    int hd = n - which * 384;
    hh[c] = hd >> 5; dd[c] = hd & 31;
  }
#pragma unroll
  for (int r = 0; r < 4; ++r) {
    int gg = m0 + wv * 16 + q4 * 4 + r;
    int ww = gg / 49, tt = gg - ww * 49;
    int wb = ww * 12;
#pragma unroll
    for (int c = 0; c < 4; ++c) {
      float val = acc[c][r] + biasv[c];
      int whi = wb + hh[c];
      if (which == 0)
        qb[(size_t)(whi * 49 + tt) * 32 + dd[c]] = (bf16)(val * QKV_SCALE);
      else if (which == 1)
        kb[(size_t)(whi * 49 + tt) * 32 + dd[c]] = (bf16)val;
      else
        vtb[(size_t)(whi * 32 + dd[c]) * 64 + tt] = (bf16)val;
    }
  }
}

// --------------------------------------------------------------------------
// Attention: one wave per (window, head). grid 6144, block 256 (4 waves).
// S = q k^T (+relpos bias +shift mask), softmax, O = P v.
// --------------------------------------------------------------------------
__global__ __launch_bounds__(256) void k_attn(
    const bf16* __restrict__ qb, const bf16* __restrict__ kb,
    const bf16* __restrict__ vtb, const float* __restrict__ table,
    bf16* __restrict__ ab) {
  __shared__ float tbl[169 * 12];
  __shared__ __align__(16) bf16 P[4][16][72];

  int tid = threadIdx.x;
  for (int i = tid; i < 169 * 12; i += 256) tbl[i] = table[i];
  __syncthreads();

  int wv = tid >> 6, lane = tid & 63;
  int l16 = lane & 15, q4 = lane >> 4;
  int whi = blockIdx.x * 4 + wv;
  int w = whi / 12, h = whi - w * 12;
  int wi = w & 63;
  int wy = wi >> 3, wx = wi & 7;

  const bf16* qq = qb + (size_t)whi * 49 * 32;
  const bf16* kk = kb + (size_t)whi * 49 * 32;
  const bf16* vv = vtb + (size_t)whi * 32 * 64;

  // j-side (key) precompute: j = c*16 + l16
  int jy4[4], jx4[4], rj4[4];
#pragma unroll
  for (int c = 0; c < 4; ++c) {
    int j = c * 16 + l16;
    int jj = j < 49 ? j : 48;
    int jy = jj / 7, jx = jj - jy * 7;
    jy4[c] = jy; jx4[c] = jx;
    int gy = wy * 7 + jy, gx = wx * 7 + jx;   // rolled-frame coords
    int ry = (gy < 49) ? 0 : ((gy < 53) ? 1 : 2);
    int rx = (gx < 49) ? 0 : ((gx < 53) ? 1 : 2);
    rj4[c] = ry * 3 + rx;
  }

  const f32x4 zero4 = {0.f, 0.f, 0.f, 0.f};

  for (int ts = 0; ts < 4; ++ts) {
    int t16 = ts * 16;
    // ---- S = q k^T -------------------------------------------------------
    int qi = t16 + l16;
    bf16x8 qf = bzero8();
    if (qi < 49) qf = *(const bf16x8*)(qq + (size_t)qi * 32 + q4 * 8);
    f32x4 s[4];
#pragma unroll
    for (int c = 0; c < 4; ++c) {
      int kj = c * 16 + l16;
      bf16x8 kf = bzero8();
      if (kj < 49) kf = *(const bf16x8*)(kk + (size_t)kj * 32 + q4 * 8);
      s[c] = __builtin_amdgcn_mfma_f32_16x16x32_bf16(qf, kf, zero4, 0, 0, 0);
    }
    // ---- bias + mask -----------------------------------------------------
#pragma unroll
    for (int r = 0; r < 4; ++r) {
      int i = t16 + q4 * 4 + r;
      int ii = i < 49 ? i : 48;
      int iy = ii / 7, ix = ii - iy * 7;
      int gy = wy * 7 + iy, gx = wx * 7 + ix;
      int riy = (gy < 49) ? 0 : ((gy < 53) ? 1 : 2);
      int rix = (gx < 49) ? 0 : ((gx < 53) ? 1 : 2);
      int ri = riy * 3 + rix;
#pragma unroll
      for (int c = 0; c < 4; ++c) {
        int j = c * 16 + l16;
        if (j < 49) {
          int rel = (iy - jy4[c] + 6) * 13 + (ix - jx4[c] + 6);
          float add = tbl[rel * 12 + h] + ((ri == rj4[c]) ? 0.f : -100.f);
          s[c][r] += add;
        } else {
          s[c][r] = -1e30f;
        }
      }
    }
    // ---- softmax per row (rows live in 16-lane quads) --------------------
#pragma unroll
    for (int r = 0; r < 4; ++r) {
      float m = fmaxf(fmaxf(s[0][r], s[1][r]), fmaxf(s[2][r], s[3][r]));
      m = fmaxf(m, __shfl_xor(m, 1));
      m = fmaxf(m, __shfl_xor(m, 2));
      m = fmaxf(m, __shfl_xor(m, 4));
      m = fmaxf(m, __shfl_xor(m, 8));
      float e0 = __expf(s[0][r] - m);
      float e1 = __expf(s[1][r] - m);
      float e2 = __expf(s[2][r] - m);
      float e3 = __expf(s[3][r] - m);
      float sm = e0 + e1 + e2 + e3;
      sm += __shfl_xor(sm, 1);
      sm += __shfl_xor(sm, 2);
      sm += __shfl_xor(sm, 4);
      sm += __shfl_xor(sm, 8);
      float inv = 1.0f / sm;
      int irow = q4 * 4 + r;
      P[wv][irow][0 * 16 + l16] = (bf16)(e0 * inv);
      P[wv][irow][1 * 16 + l16] = (bf16)(e1 * inv);
      P[wv][irow][2 * 16 + l16] = (bf16)(e2 * inv);
      P[wv][irow][3 * 16 + l16] = (bf16)(e3 * inv);
    }
    __syncthreads();
    // ---- O = P v ---------------------------------------------------------
    bf16x8 p0 = *(const bf16x8*)&P[wv][l16][q4 * 8];
    bf16x8 p1 = *(const bf16x8*)&P[wv][l16][32 + q4 * 8];
    f32x4 o[2];
#pragma unroll
    for (int c2 = 0; c2 < 2; ++c2) {
      bf16x8 v0 = *(const bf16x8*)(vv + (size_t)(c2 * 16 + l16) * 64 + q4 * 8);
      bf16x8 v1 = *(const bf16x8*)(vv + (size_t)(c2 * 16 + l16) * 64 + 32 + q4 * 8);
      o[c2] = __builtin_amdgcn_mfma_f32_16x16x32_bf16(p0, v0, zero4, 0, 0, 0);
      o[c2] = __builtin_amdgcn_mfma_f32_16x16x32_bf16(p1, v1, o[c2], 0, 0, 0);
    }
#pragma unroll
    for (int c2 = 0; c2 < 2; ++c2) {
#pragma unroll
      for (int r = 0; r < 4; ++r) {
        int i = t16 + q4 * 4 + r;
        if (i < 49)
          ab[(size_t)(w * 49 + i) * 384 + h * 32 + c2 * 16 + l16] = (bf16)o[c2][r];
      }
    }
    __syncthreads();   // P reused next strip
  }
}

// --------------------------------------------------------------------------
// Proj GEMM [GTOK x 384, K=384] + scatter (window merge + roll +3) to fp32.
// grid (1568, 6), block 256.
// --------------------------------------------------------------------------
__global__ __launch_bounds__(256) void k_proj(
    const bf16* __restrict__ ab, const float* __restrict__ wp,
    const float* __restrict__ bp, float* __restrict__ out) {
  __shared__ __align__(16) bf16 As[64][40];
  __shared__ __align__(16) bf16 Bs[64][40];

  int tid = threadIdx.x;
  int m0 = blockIdx.x * 64;
  int n0 = blockIdx.y * 64;
  int lrow = tid >> 2;
  int lcol = (tid & 3) * 8;
  const bf16* arow = ab + (size_t)(m0 + lrow) * 384;
  const float* brow = wp + (size_t)(n0 + lrow) * 384;

  int wv = tid >> 6, lane = tid & 63;
  int l16 = lane & 15, q4 = lane >> 4;

  f32x4 acc[4];
#pragma unroll
  for (int c = 0; c < 4; ++c) acc[c] = (f32x4){0.f, 0.f, 0.f, 0.f};

  for (int k0 = 0; k0 < 384; k0 += 32) {
    bf16x8 av = *(const bf16x8*)(arow + k0 + lcol);
    float4 b0 = *(const float4*)(brow + k0 + lcol);
    float4 b1 = *(const float4*)(brow + k0 + lcol + 4);
    __syncthreads();
    bf16x8 bv;
    bv[0] = (bf16)b0.x; bv[1] = (bf16)b0.y; bv[2] = (bf16)b0.z; bv[3] = (bf16)b0.w;
    bv[4] = (bf16)b1.x; bv[5] = (bf16)b1.y; bv[6] = (bf16)b1.z; bv[7] = (bf16)b1.w;
    *(bf16x8*)&As[lrow][lcol] = av;
    *(bf16x8*)&Bs[lrow][lcol] = bv;
    __syncthreads();
    bf16x8 af = *(const bf16x8*)&As[wv * 16 + l16][q4 * 8];
#pragma unroll
    for (int c = 0; c < 4; ++c) {
      bf16x8 bfm = *(const bf16x8*)&Bs[c * 16 + l16][q4 * 8];
      acc[c] = __builtin_amdgcn_mfma_f32_16x16x32_bf16(af, bfm, acc[c], 0, 0, 0);
    }
  }

  float biasv[4];
#pragma unroll
  for (int c = 0; c < 4; ++c) biasv[c] = bp[n0 + c * 16 + l16];
#pragma unroll
  for (int r = 0; r < 4; ++r) {
    int g = m0 + wv * 16 + q4 * 4 + r;
    int w = g / 49, t = g - w * 49;
    int b = w >> 6, wi = w & 63;
    int wy = wi >> 3, wx = wi & 7;
    int ty = t / 7, tx = t - ty * 7;
    int gy = wy * 7 + ty + 3; if (gy >= 56) gy -= 56;
    int gx = wx * 7 + tx + 3; if (gx >= 56) gx -= 56;
    float* orow = out + (size_t)(((b * 56 + gy) * 56 + gx)) * 384 + n0;
#pragma unroll
    for (int c = 0; c < 4; ++c) orow[c * 16 + l16] = acc[c][r] + biasv[c];
  }
}

// --------------------------------------------------------------------------
extern "C" void kernel_launch(void* const* d_in, const int* in_sizes, int n_in,
                              void* d_out, int out_size, void* d_ws,
                              size_t ws_size, hipStream_t stream) {
  const float* x     = (const float*)d_in[0];
  const float* wqkv  = (const float*)d_in[1];
  const float* bqkv  = (const float*)d_in[2];
  const float* wproj = (const float*)d_in[3];
  const float* bproj = (const float*)d_in[4];
  const float* table = (const float*)d_in[5];
  float* out = (float*)d_out;

  char* ws = (char*)d_ws;
  bf16* qb  = (bf16*)(ws + QB_OFF);
  bf16* kb  = (bf16*)(ws + KB_OFF);
  bf16* vtb = (bf16*)(ws + VT_OFF);
  bf16* ab  = (bf16*)(ws + AB_OFF);

  k_zpad<<<dim3((WHN * 32 + 255) / 256), dim3(256), 0, stream>>>(vtb);
  k_qkv<<<dim3(1568, 18), dim3(256), 0, stream>>>(x, wqkv, bqkv, qb, kb, vtb);
  k_attn<<<dim3(6144), dim3(256), 0, stream>>>(qb, kb, vtb, table, ab);
  k_proj<<<dim3(1568, 6), dim3(256), 0, stream>>>(ab, wproj, bproj, out);
}

// Round 2
// 639.372 us; speedup vs baseline: 1.4673x; 1.4673x over previous
//
#include <hip/hip_runtime.h>

// ---------------------------------------------------------------------------
// Shifted-window attention (Swin), MI355X bf16-MFMA implementation, round 2.
// B=32, H=W=56, C=384, nh=12, dh=32, ws=7 (T=49), shift=3, windows=2048.
// Pipeline: gather(x->bf16, rolled order) + cvt weights + frag-ordered
//           bias/mask precompute -> m97-style qkv GEMM (global_load_lds,
//           128x128 tiles, swizzled LDS) -> barrier-free per-wave attention ->
//           m97-style proj GEMM with pixel scatter.
// ---------------------------------------------------------------------------

typedef __bf16 bf16;
typedef __bf16 bf16x8 __attribute__((ext_vector_type(8)));
typedef __bf16 bf16x4 __attribute__((ext_vector_type(4)));
typedef float f32x4 __attribute__((ext_vector_type(4)));

#define NWIN   2048
#define WHN    24576
#define GTOK   100352
#define QKV_SCALE 0.17677669529663687f

// workspace offsets (bytes); total 326,762,496 <= 331,874,304 (known safe)
#define QB_OFF 0u
#define KB_OFF 77070336u
#define VT_OFF 154140672u      // vT [WHN][32][56]
#define XG_OFF 242221056u      // xg bf16 [GTOK][384]; ab overlays after qkv
#define BM_OFF 319291392u      // bias+mask bf16, fragment order [768][4096]
#define WQ_OFF 325582848u      // wqkv bf16 [1152][384]
#define WP_OFF 326467584u      // wproj bf16 [384][384]

__device__ inline void gld16(const bf16* g, bf16* l) {
  __builtin_amdgcn_global_load_lds(
      (const __attribute__((address_space(1))) void*)g,
      (__attribute__((address_space(3))) void*)l, 16, 0, 0);
}

// --------------------------------------------------------------------------
// gather: roll(-3,-3) + window partition + fp32->bf16.  xg[g][c].
// --------------------------------------------------------------------------
__global__ __launch_bounds__(256) void k_gather(const float* __restrict__ x,
                                                bf16* __restrict__ xg) {
  int idx = blockIdx.x * 256 + threadIdx.x;       // < GTOK*48
  int g = idx / 48, cg = idx - g * 48;
  int w = g / 49, t = g - w * 49;
  int b = w >> 6, wi = w & 63;
  int wy = wi >> 3, wx = wi & 7;
  int ty = t / 7, tx = t - ty * 7;
  int sy = wy * 7 + ty + 3; if (sy >= 56) sy -= 56;
  int sx = wx * 7 + tx + 3; if (sx >= 56) sx -= 56;
  const float* src = x + (size_t)((b * 56 + sy) * 56 + sx) * 384 + cg * 8;
  float4 a0 = *(const float4*)src;
  float4 a1 = *(const float4*)(src + 4);
  bf16x8 o;
  o[0] = (bf16)a0.x; o[1] = (bf16)a0.y; o[2] = (bf16)a0.z; o[3] = (bf16)a0.w;
  o[4] = (bf16)a1.x; o[5] = (bf16)a1.y; o[6] = (bf16)a1.z; o[7] = (bf16)a1.w;
  *(bf16x8*)(xg + (size_t)g * 384 + cg * 8) = o;
}

// --------------------------------------------------------------------------
// convert both weight matrices to bf16
// --------------------------------------------------------------------------
__global__ __launch_bounds__(256) void k_cvt(const float* __restrict__ wqkv,
                                             const float* __restrict__ wproj,
                                             bf16* __restrict__ wq,
                                             bf16* __restrict__ wp) {
  int idx = blockIdx.x * 256 + threadIdx.x;       // < 73728
  const float* src; bf16* dst; int off;
  if (idx < 55296) { src = wqkv; dst = wq; off = idx * 8; }
  else             { src = wproj; dst = wp; off = (idx - 55296) * 8; }
  float4 a0 = *(const float4*)(src + off);
  float4 a1 = *(const float4*)(src + off + 4);
  bf16x8 o;
  o[0] = (bf16)a0.x; o[1] = (bf16)a0.y; o[2] = (bf16)a0.z; o[3] = (bf16)a0.w;
  o[4] = (bf16)a1.x; o[5] = (bf16)a1.y; o[6] = (bf16)a1.z; o[7] = (bf16)a1.w;
  *(bf16x8*)(dst + off) = o;
}

// --------------------------------------------------------------------------
// fragment-ordered bias+mask: bm[(wi*12+h)*4096 + (ts*4+c)*256 + lane*4 + r]
// element (i = ts*16+(lane>>4)*4+r, j = c*16+(lane&15)).
// j>=49 -> -30000 ; i>=49 -> 0 ; else relpos bias + shift mask.
// --------------------------------------------------------------------------
__global__ __launch_bounds__(256) void k_bias(const float* __restrict__ table,
                                              bf16* __restrict__ bm) {
  int idx = blockIdx.x * 256 + threadIdx.x;       // < 3,145,728
  int r = idx & 3;
  int lane = (idx >> 2) & 63;
  int c = (idx >> 8) & 3;
  int ts = (idx >> 10) & 3;
  int comb = idx >> 12;                            // < 768
  int h = comb % 12, wi = comb / 12;
  int i = ts * 16 + ((lane >> 4) << 2) + r;
  int j = c * 16 + (lane & 15);
  float v;
  if (j >= 49) v = -30000.f;
  else if (i >= 49) v = 0.f;
  else {
    int wy = wi >> 3, wx = wi & 7;
    int iy = i / 7, ix = i - iy * 7;
    int jy = j / 7, jx = j - jy * 7;
    int rel = (iy - jy + 6) * 13 + (ix - jx + 6);
    int gyi = wy * 7 + iy, gxi = wx * 7 + ix;
    int gyj = wy * 7 + jy, gxj = wx * 7 + jx;
    int ri = ((gyi < 49) ? 0 : ((gyi < 53) ? 1 : 2)) * 3 +
             ((gxi < 49) ? 0 : ((gxi < 53) ? 1 : 2));
    int rj = ((gyj < 49) ? 0 : ((gyj < 53) ? 1 : 2)) * 3 +
             ((gxj < 49) ? 0 : ((gxj < 53) ? 1 : 2));
    v = table[rel * 12 + h] + ((ri == rj) ? 0.f : -100.f);
  }
  bm[idx] = (bf16)v;
}

// --------------------------------------------------------------------------
// zero the t=49..55 padding of vT [WHN][32][56]
// --------------------------------------------------------------------------
__global__ __launch_bounds__(256) void k_zpad(bf16* __restrict__ vtb) {
  int r = blockIdx.x * 256 + threadIdx.x;          // < WHN*32
  bf16* p = vtb + (size_t)r * 56 + 49;
#pragma unroll
  for (int i = 0; i < 7; ++i) p[i] = (bf16)0.0f;
}

// --------------------------------------------------------------------------
// QKV GEMM [GTOK x 1152, K=384], A=xg bf16, B=wq bf16.
// m97 structure: 128x128 tile, BK=64, global_load_lds w=16, XOR-swizzled LDS.
// grid (9, 784): blockIdx.x = n-block (fast) -> A-strip L2 reuse.
// --------------------------------------------------------------------------
__global__ __launch_bounds__(256, 3) void k_qkv(
    const bf16* __restrict__ xg, const bf16* __restrict__ wg,
    const float* __restrict__ bqkv, bf16* __restrict__ qb,
    bf16* __restrict__ kb, bf16* __restrict__ vtb) {
  __shared__ __align__(16) bf16 As[128 * 64];
  __shared__ __align__(16) bf16 Bs[128 * 64];

  int tid = threadIdx.x;
  int wv = tid >> 6, lane = tid & 63, l16 = lane & 15, q4 = lane >> 4;
  int wr = wv >> 1, wc = wv & 1;
  int nb = blockIdx.x;
  int m0 = blockIdx.y * 128;
  int n0 = nb * 128;

  int srow = lane >> 3;        // 0..7
  int scg = lane & 7;          // chunk 0..7

  f32x4 acc[4][4];
#pragma unroll
  for (int a = 0; a < 4; ++a)
#pragma unroll
    for (int b = 0; b < 4; ++b) acc[a][b] = (f32x4){0.f, 0.f, 0.f, 0.f};

  for (int k0 = 0; k0 < 384; k0 += 64) {
    __syncthreads();
#pragma unroll
    for (int s = 0; s < 4; ++s) {
      int row = (wv * 4 + s) * 8 + srow;
      int gc = (scg ^ (row & 7)) * 8;
      gld16(xg + (size_t)(m0 + row) * 384 + k0 + gc, As + (wv * 4 + s) * 512);
      gld16(wg + (size_t)(n0 + row) * 384 + k0 + gc, Bs + (wv * 4 + s) * 512);
    }
    __syncthreads();
#pragma unroll
    for (int kk = 0; kk < 2; ++kk) {
      bf16x8 af[4], bfr[4];
#pragma unroll
      for (int mi = 0; mi < 4; ++mi) {
        int m = wr * 64 + mi * 16 + l16;
        int g = kk * 4 + q4;
        af[mi] = *(const bf16x8*)(As + m * 64 + ((g ^ (m & 7)) * 8));
      }
#pragma unroll
      for (int ci = 0; ci < 4; ++ci) {
        int n = wc * 64 + ci * 16 + l16;
        int g = kk * 4 + q4;
        bfr[ci] = *(const bf16x8*)(Bs + n * 64 + ((g ^ (n & 7)) * 8));
      }
#pragma unroll
      for (int mi = 0; mi < 4; ++mi)
#pragma unroll
        for (int ci = 0; ci < 4; ++ci)
          acc[mi][ci] =
              __builtin_amdgcn_mfma_f32_16x16x32_bf16(af[mi], bfr[ci], acc[mi][ci], 0, 0, 0);
    }
  }

  int which = nb / 3;          // 0:q 1:k 2:v
  float bias4[4]; int h4[4], d4[4];
#pragma unroll
  for (int ci = 0; ci < 4; ++ci) {
    int n = n0 + wc * 64 + ci * 16 + l16;
    bias4[ci] = bqkv[n];
    int hd = n - which * 384;
    h4[ci] = hd >> 5; d4[ci] = hd & 31;
  }
#pragma unroll
  for (int mi = 0; mi < 4; ++mi) {
#pragma unroll
    for (int r = 0; r < 4; ++r) {
      int mrow = m0 + wr * 64 + mi * 16 + q4 * 4 + r;
      int w = mrow / 49, tt = mrow - w * 49;
      int wb = w * 12;
#pragma unroll
      for (int ci = 0; ci < 4; ++ci) {
        float val = acc[mi][ci][r] + bias4[ci];
        int whi = wb + h4[ci];
        if (which == 0)
          qb[(size_t)(whi * 49 + tt) * 32 + d4[ci]] = (bf16)(val * QKV_SCALE);
        else if (which == 1)
          kb[(size_t)(whi * 49 + tt) * 32 + d4[ci]] = (bf16)val;
        else
          vtb[(size_t)(whi * 32 + d4[ci]) * 56 + tt] = (bf16)val;
      }
    }
  }
}

// --------------------------------------------------------------------------
// Attention: one wave per (window, head), barrier-free. grid 6144 x 256.
// --------------------------------------------------------------------------
__global__ __launch_bounds__(256) void k_attn(
    const bf16* __restrict__ qb, const bf16* __restrict__ kb,
    const bf16* __restrict__ vtb, const bf16* __restrict__ bm,
    bf16* __restrict__ ab) {
  __shared__ __align__(16) bf16 P[4][16][72];

  int tid = threadIdx.x;
  int wv = tid >> 6, lane = tid & 63, l16 = lane & 15, q4 = lane >> 4;
  int whi = blockIdx.x * 4 + wv;
  int w = whi / 12, h = whi - w * 12;
  int wi = w & 63;

  const bf16* qq = qb + (size_t)whi * 1568;
  const bf16* kk = kb + (size_t)whi * 1568;
  const bf16* vv = vtb + (size_t)whi * 1792;
  const bf16* bmb = bm + ((size_t)(wi * 12 + h) << 12);

  bf16x8 z8;
#pragma unroll
  for (int i = 0; i < 8; ++i) z8[i] = (bf16)0.0f;

  bf16x8 kf[4];
#pragma unroll
  for (int c = 0; c < 4; ++c)
    kf[c] = *(const bf16x8*)(kk + (c * 16 + l16) * 32 + q4 * 8);
  bf16x8 v0[2], v1[2];
#pragma unroll
  for (int c2 = 0; c2 < 2; ++c2) {
    v0[c2] = *(const bf16x8*)(vv + (c2 * 16 + l16) * 56 + q4 * 8);
    v1[c2] = (q4 < 3) ? *(const bf16x8*)(vv + (c2 * 16 + l16) * 56 + 32 + q4 * 8)
                      : z8;
  }

  const f32x4 zero4 = {0.f, 0.f, 0.f, 0.f};

  for (int ts = 0; ts < 4; ++ts) {
    bf16x8 qf = *(const bf16x8*)(qq + (ts * 16 + l16) * 32 + q4 * 8);
    f32x4 s[4];
#pragma unroll
    for (int c = 0; c < 4; ++c)
      s[c] = __builtin_amdgcn_mfma_f32_16x16x32_bf16(qf, kf[c], zero4, 0, 0, 0);
#pragma unroll
    for (int c = 0; c < 4; ++c) {
      bf16x4 bv = *(const bf16x4*)(bmb + (ts * 4 + c) * 256 + lane * 4);
#pragma unroll
      for (int r = 0; r < 4; ++r) s[c][r] += (float)bv[r];
    }
#pragma unroll
    for (int r = 0; r < 4; ++r) {
      float m = fmaxf(fmaxf(s[0][r], s[1][r]), fmaxf(s[2][r], s[3][r]));
      m = fmaxf(m, __shfl_xor(m, 1));
      m = fmaxf(m, __shfl_xor(m, 2));
      m = fmaxf(m, __shfl_xor(m, 4));
      m = fmaxf(m, __shfl_xor(m, 8));
      float e0 = __expf(s[0][r] - m);
      float e1 = __expf(s[1][r] - m);
      float e2 = __expf(s[2][r] - m);
      float e3 = __expf(s[3][r] - m);
      float sm = e0 + e1 + e2 + e3;
      sm += __shfl_xor(sm, 1);
      sm += __shfl_xor(sm, 2);
      sm += __shfl_xor(sm, 4);
      sm += __shfl_xor(sm, 8);
      float inv = 1.0f / sm;
      int ir = q4 * 4 + r;
      P[wv][ir][l16] = (bf16)(e0 * inv);
      P[wv][ir][16 + l16] = (bf16)(e1 * inv);
      P[wv][ir][32 + l16] = (bf16)(e2 * inv);
      P[wv][ir][48 + l16] = (bf16)(e3 * inv);
    }
    __builtin_amdgcn_wave_barrier();   // pin ds_write < ds_read order
    bf16x8 p0 = *(const bf16x8*)&P[wv][l16][q4 * 8];
    bf16x8 p1 = *(const bf16x8*)&P[wv][l16][32 + q4 * 8];
    f32x4 o0 = __builtin_amdgcn_mfma_f32_16x16x32_bf16(p0, v0[0], zero4, 0, 0, 0);
    o0 = __builtin_amdgcn_mfma_f32_16x16x32_bf16(p1, v1[0], o0, 0, 0, 0);
    f32x4 o1 = __builtin_amdgcn_mfma_f32_16x16x32_bf16(p0, v0[1], zero4, 0, 0, 0);
    o1 = __builtin_amdgcn_mfma_f32_16x16x32_bf16(p1, v1[1], o1, 0, 0, 0);
    __builtin_amdgcn_wave_barrier();   // pin ds_read < next strip's ds_write
#pragma unroll
    for (int r = 0; r < 4; ++r) {
      int i = ts * 16 + q4 * 4 + r;
      if (i < 49) {
        bf16* dst = ab + (size_t)(w * 49 + i) * 384 + h * 32;
        dst[l16] = (bf16)o0[r];
        dst[16 + l16] = (bf16)o1[r];
      }
    }
  }
}

// --------------------------------------------------------------------------
// Proj GEMM [GTOK x 384, K=384] + pixel scatter (roll +3) to fp32 out.
// grid (3, 784).
// --------------------------------------------------------------------------
__global__ __launch_bounds__(256, 3) void k_proj(
    const bf16* __restrict__ ab, const bf16* __restrict__ wp,
    const float* __restrict__ bp, float* __restrict__ out) {
  __shared__ __align__(16) bf16 As[128 * 64];
  __shared__ __align__(16) bf16 Bs[128 * 64];

  int tid = threadIdx.x;
  int wv = tid >> 6, lane = tid & 63, l16 = lane & 15, q4 = lane >> 4;
  int wr = wv >> 1, wc = wv & 1;
  int m0 = blockIdx.y * 128;
  int n0 = blockIdx.x * 128;

  int srow = lane >> 3;
  int scg = lane & 7;

  f32x4 acc[4][4];
#pragma unroll
  for (int a = 0; a < 4; ++a)
#pragma unroll
    for (int b = 0; b < 4; ++b) acc[a][b] = (f32x4){0.f, 0.f, 0.f, 0.f};

  for (int k0 = 0; k0 < 384; k0 += 64) {
    __syncthreads();
#pragma unroll
    for (int s = 0; s < 4; ++s) {
      int row = (wv * 4 + s) * 8 + srow;
      int gc = (scg ^ (row & 7)) * 8;
      gld16(ab + (size_t)(m0 + row) * 384 + k0 + gc, As + (wv * 4 + s) * 512);
      gld16(wp + (size_t)(n0 + row) * 384 + k0 + gc, Bs + (wv * 4 + s) * 512);
    }
    __syncthreads();
#pragma unroll
    for (int kk = 0; kk < 2; ++kk) {
      bf16x8 af[4], bfr[4];
#pragma unroll
      for (int mi = 0; mi < 4; ++mi) {
        int m = wr * 64 + mi * 16 + l16;
        int g = kk * 4 + q4;
        af[mi] = *(const bf16x8*)(As + m * 64 + ((g ^ (m & 7)) * 8));
      }
#pragma unroll
      for (int ci = 0; ci < 4; ++ci) {
        int n = wc * 64 + ci * 16 + l16;
        int g = kk * 4 + q4;
        bfr[ci] = *(const bf16x8*)(Bs + n * 64 + ((g ^ (n & 7)) * 8));
      }
#pragma unroll
      for (int mi = 0; mi < 4; ++mi)
#pragma unroll
        for (int ci = 0; ci < 4; ++ci)
          acc[mi][ci] =
              __builtin_amdgcn_mfma_f32_16x16x32_bf16(af[mi], bfr[ci], acc[mi][ci], 0, 0, 0);
    }
  }

  float bias4[4]; int col4[4];
#pragma unroll
  for (int ci = 0; ci < 4; ++ci) {
    col4[ci] = n0 + wc * 64 + ci * 16 + l16;
    bias4[ci] = bp[col4[ci]];
  }
#pragma unroll
  for (int mi = 0; mi < 4; ++mi) {
#pragma unroll
    for (int r = 0; r < 4; ++r) {
      int mrow = m0 + wr * 64 + mi * 16 + q4 * 4 + r;
      int w = mrow / 49, t = mrow - w * 49;
      int b = w >> 6, wi = w & 63;
      int wy = wi >> 3, wx = wi & 7;
      int ty = t / 7, tx = t - ty * 7;
      int gy = wy * 7 + ty + 3; if (gy >= 56) gy -= 56;
      int gx = wx * 7 + tx + 3; if (gx >= 56) gx -= 56;
      float* orow = out + (size_t)((b * 56 + gy) * 56 + gx) * 384;
#pragma unroll
      for (int ci = 0; ci < 4; ++ci) orow[col4[ci]] = acc[mi][ci][r] + bias4[ci];
    }
  }
}

// --------------------------------------------------------------------------
extern "C" void kernel_launch(void* const* d_in, const int* in_sizes, int n_in,
                              void* d_out, int out_size, void* d_ws,
                              size_t ws_size, hipStream_t stream) {
  const float* x     = (const float*)d_in[0];
  const float* wqkv  = (const float*)d_in[1];
  const float* bqkv  = (const float*)d_in[2];
  const float* wproj = (const float*)d_in[3];
  const float* bproj = (const float*)d_in[4];
  const float* table = (const float*)d_in[5];
  float* out = (float*)d_out;

  char* ws = (char*)d_ws;
  bf16* qb  = (bf16*)(ws + QB_OFF);
  bf16* kb  = (bf16*)(ws + KB_OFF);
  bf16* vtb = (bf16*)(ws + VT_OFF);
  bf16* xg  = (bf16*)(ws + XG_OFF);
  bf16* ab  = (bf16*)(ws + XG_OFF);   // overlays xg (dead after k_qkv)
  bf16* bmb = (bf16*)(ws + BM_OFF);
  bf16* wqg = (bf16*)(ws + WQ_OFF);
  bf16* wpg = (bf16*)(ws + WP_OFF);

  k_gather<<<dim3(18816), dim3(256), 0, stream>>>(x, xg);
  k_cvt<<<dim3(288), dim3(256), 0, stream>>>(wqkv, wproj, wqg, wpg);
  k_bias<<<dim3(12288), dim3(256), 0, stream>>>(table, bmb);
  k_zpad<<<dim3(3072), dim3(256), 0, stream>>>(vtb);
  k_qkv<<<dim3(9, 784), dim3(256), 0, stream>>>(xg, wqg, bqkv, qb, kb, vtb);
  k_attn<<<dim3(6144), dim3(256), 0, stream>>>(qb, kb, vtb, bmb, ab);
  k_proj<<<dim3(3, 784), dim3(256), 0, stream>>>(ab, wpg, bproj, out);
}

// Round 3
// 524.242 us; speedup vs baseline: 1.7896x; 1.2196x over previous
//
#include <hip/hip_runtime.h>

// ---------------------------------------------------------------------------
// Shifted-window attention (Swin), MI355X bf16-MFMA, round 3.
// Changes vs r2: XCD-aware swizzle on both GEMMs (n-tiles of one m-strip stay
// in one XCD's L2), V stored untransposed (coalesced epilogue; PV B-frag via
// ushort gather; masked P cols are exactly 0 so no V padding needed),
// prep kernels merged.
// ---------------------------------------------------------------------------

typedef __bf16 bf16;
typedef __bf16 bf16x8 __attribute__((ext_vector_type(8)));
typedef __bf16 bf16x4 __attribute__((ext_vector_type(4)));
typedef float f32x4 __attribute__((ext_vector_type(4)));

#define NWIN   2048
#define WHN    24576
#define GTOK   100352
#define QKV_SCALE 0.17677669529663687f

// workspace offsets (bytes); total 315,752,448 <= 331,874,304 (known safe)
#define QB_OFF 0u
#define KB_OFF 77070336u
#define VB_OFF 154140672u      // v [WHN][49][32]
#define XG_OFF 231211008u      // xg bf16 [GTOK][384]; ab overlays after qkv
#define BM_OFF 308281344u      // bias+mask bf16, fragment order [768][4096]
#define WQ_OFF 314572800u      // wqkv bf16 [1152][384]
#define WP_OFF 315457536u      // wproj bf16 [384][384]

__device__ inline void gld16(const bf16* g, bf16* l) {
  __builtin_amdgcn_global_load_lds(
      (const __attribute__((address_space(1))) void*)g,
      (__attribute__((address_space(3))) void*)l, 16, 0, 0);
}

// --------------------------------------------------------------------------
// merged prep: [0,18816) gather  [18816,19104) weight cvt  [19104,31392) bias
// --------------------------------------------------------------------------
__global__ __launch_bounds__(256) void k_prep(
    const float* __restrict__ x, const float* __restrict__ wqkv,
    const float* __restrict__ wproj, const float* __restrict__ table,
    bf16* __restrict__ xg, bf16* __restrict__ wq, bf16* __restrict__ wp,
    bf16* __restrict__ bm) {
  int blk = blockIdx.x;
  if (blk < 18816) {
    // gather: roll(-3,-3) + window partition + fp32->bf16
    int idx = blk * 256 + threadIdx.x;            // < GTOK*48
    int g = idx / 48, cg = idx - g * 48;
    int w = g / 49, t = g - w * 49;
    int b = w >> 6, wi = w & 63;
    int wy = wi >> 3, wx = wi & 7;
    int ty = t / 7, tx = t - ty * 7;
    int sy = wy * 7 + ty + 3; if (sy >= 56) sy -= 56;
    int sx = wx * 7 + tx + 3; if (sx >= 56) sx -= 56;
    const float* src = x + (size_t)((b * 56 + sy) * 56 + sx) * 384 + cg * 8;
    float4 a0 = *(const float4*)src;
    float4 a1 = *(const float4*)(src + 4);
    bf16x8 o;
    o[0] = (bf16)a0.x; o[1] = (bf16)a0.y; o[2] = (bf16)a0.z; o[3] = (bf16)a0.w;
    o[4] = (bf16)a1.x; o[5] = (bf16)a1.y; o[6] = (bf16)a1.z; o[7] = (bf16)a1.w;
    *(bf16x8*)(xg + (size_t)g * 384 + cg * 8) = o;
  } else if (blk < 19104) {
    int idx = (blk - 18816) * 256 + threadIdx.x;  // < 73728
    const float* src; bf16* dst; int off;
    if (idx < 55296) { src = wqkv; dst = wq; off = idx * 8; }
    else             { src = wproj; dst = wp; off = (idx - 55296) * 8; }
    float4 a0 = *(const float4*)(src + off);
    float4 a1 = *(const float4*)(src + off + 4);
    bf16x8 o;
    o[0] = (bf16)a0.x; o[1] = (bf16)a0.y; o[2] = (bf16)a0.z; o[3] = (bf16)a0.w;
    o[4] = (bf16)a1.x; o[5] = (bf16)a1.y; o[6] = (bf16)a1.z; o[7] = (bf16)a1.w;
    *(bf16x8*)(dst + off) = o;
  } else {
    // frag-ordered bias+mask: bm[(wi*12+h)*4096 + (ts*4+c)*256 + lane*4 + r]
    int idx = (blk - 19104) * 256 + threadIdx.x;  // < 3,145,728
    int r = idx & 3;
    int lane = (idx >> 2) & 63;
    int c = (idx >> 8) & 3;
    int ts = (idx >> 10) & 3;
    int comb = idx >> 12;                          // < 768
    int h = comb % 12, wi = comb / 12;
    int i = ts * 16 + ((lane >> 4) << 2) + r;
    int j = c * 16 + (lane & 15);
    float v;
    if (j >= 49) v = -30000.f;
    else if (i >= 49) v = 0.f;
    else {
      int wy = wi >> 3, wx = wi & 7;
      int iy = i / 7, ix = i - iy * 7;
      int jy = j / 7, jx = j - jy * 7;
      int rel = (iy - jy + 6) * 13 + (ix - jx + 6);
      int gyi = wy * 7 + iy, gxi = wx * 7 + ix;
      int gyj = wy * 7 + jy, gxj = wx * 7 + jx;
      int ri = ((gyi < 49) ? 0 : ((gyi < 53) ? 1 : 2)) * 3 +
               ((gxi < 49) ? 0 : ((gxi < 53) ? 1 : 2));
      int rj = ((gyj < 49) ? 0 : ((gyj < 53) ? 1 : 2)) * 3 +
               ((gxj < 49) ? 0 : ((gxj < 53) ? 1 : 2));
      v = table[rel * 12 + h] + ((ri == rj) ? 0.f : -100.f);
    }
    bm[idx] = (bf16)v;
  }
}

// --------------------------------------------------------------------------
// QKV GEMM [GTOK x 1152, K=384]. 128x128 tile, BK=64, global_load_lds w=16,
// XOR-swizzled LDS. XCD swizzle: xcd=bid&7, n fastest within XCD.
// --------------------------------------------------------------------------
__global__ __launch_bounds__(256, 3) void k_qkv(
    const bf16* __restrict__ xg, const bf16* __restrict__ wg,
    const float* __restrict__ bqkv, bf16* __restrict__ qb,
    bf16* __restrict__ kb, bf16* __restrict__ vb) {
  __shared__ __align__(16) bf16 As[128 * 64];
  __shared__ __align__(16) bf16 Bs[128 * 64];

  int tid = threadIdx.x;
  int wv = tid >> 6, lane = tid & 63, l16 = lane & 15, q4 = lane >> 4;
  int wr = wv >> 1, wc = wv & 1;
  int bid = blockIdx.x;              // 7056
  int xcd = bid & 7, s = bid >> 3;
  int nb = s % 9, mt = s / 9;        // nb fastest within an XCD
  int m0 = (mt * 8 + xcd) * 128;
  int n0 = nb * 128;

  int srow = lane >> 3;
  int scg = lane & 7;

  f32x4 acc[4][4];
#pragma unroll
  for (int a = 0; a < 4; ++a)
#pragma unroll
    for (int b = 0; b < 4; ++b) acc[a][b] = (f32x4){0.f, 0.f, 0.f, 0.f};

  for (int k0 = 0; k0 < 384; k0 += 64) {
    __syncthreads();
#pragma unroll
    for (int st = 0; st < 4; ++st) {
      int row = (wv * 4 + st) * 8 + srow;
      int gc = (scg ^ (row & 7)) * 8;
      gld16(xg + (size_t)(m0 + row) * 384 + k0 + gc, As + (wv * 4 + st) * 512);
      gld16(wg + (size_t)(n0 + row) * 384 + k0 + gc, Bs + (wv * 4 + st) * 512);
    }
    __syncthreads();
#pragma unroll
    for (int kk = 0; kk < 2; ++kk) {
      bf16x8 af[4], bfr[4];
#pragma unroll
      for (int mi = 0; mi < 4; ++mi) {
        int m = wr * 64 + mi * 16 + l16;
        int g = kk * 4 + q4;
        af[mi] = *(const bf16x8*)(As + m * 64 + ((g ^ (m & 7)) * 8));
      }
#pragma unroll
      for (int ci = 0; ci < 4; ++ci) {
        int n = wc * 64 + ci * 16 + l16;
        int g = kk * 4 + q4;
        bfr[ci] = *(const bf16x8*)(Bs + n * 64 + ((g ^ (n & 7)) * 8));
      }
#pragma unroll
      for (int mi = 0; mi < 4; ++mi)
#pragma unroll
        for (int ci = 0; ci < 4; ++ci)
          acc[mi][ci] =
              __builtin_amdgcn_mfma_f32_16x16x32_bf16(af[mi], bfr[ci], acc[mi][ci], 0, 0, 0);
    }
  }

  int which = nb / 3;                // 0:q 1:k 2:v (uniform per block)
  float bias4[4]; int h4[4], d4[4];
#pragma unroll
  for (int ci = 0; ci < 4; ++ci) {
    int n = n0 + wc * 64 + ci * 16 + l16;
    bias4[ci] = bqkv[n];
    int hd = n - which * 384;
    h4[ci] = hd >> 5; d4[ci] = hd & 31;
  }
#pragma unroll
  for (int mi = 0; mi < 4; ++mi) {
#pragma unroll
    for (int r = 0; r < 4; ++r) {
      int mrow = m0 + wr * 64 + mi * 16 + q4 * 4 + r;
      int w = mrow / 49, tt = mrow - w * 49;
      int wb = w * 12;
#pragma unroll
      for (int ci = 0; ci < 4; ++ci) {
        float val = acc[mi][ci][r] + bias4[ci];
        size_t addr = (size_t)((wb + h4[ci]) * 49 + tt) * 32 + d4[ci];
        if (which == 0)
          qb[addr] = (bf16)(val * QKV_SCALE);
        else if (which == 1)
          kb[addr] = (bf16)val;
        else
          vb[addr] = (bf16)val;
      }
    }
  }
}

// --------------------------------------------------------------------------
// Attention: one wave per (window, head), barrier-free. grid 6144 x 256.
// Masked P columns (j>=49) are exactly 0 -> V needs no padding rows.
// --------------------------------------------------------------------------
__global__ __launch_bounds__(256) void k_attn(
    const bf16* __restrict__ qb, const bf16* __restrict__ kb,
    const bf16* __restrict__ vb, const bf16* __restrict__ bm,
    bf16* __restrict__ ab) {
  __shared__ __align__(16) bf16 P[4][16][72];

  int tid = threadIdx.x;
  int wv = tid >> 6, lane = tid & 63, l16 = lane & 15, q4 = lane >> 4;
  int whi = blockIdx.x * 4 + wv;
  int w = whi / 12, h = whi - w * 12;
  int wi = w & 63;

  const bf16* qq = qb + (size_t)whi * 1568;
  const bf16* kk = kb + (size_t)whi * 1568;
  const bf16* vv = vb + (size_t)whi * 1568;
  const bf16* bmb = bm + ((size_t)(wi * 12 + h) << 12);

  // K fragments (rows >=49 are garbage; masked by bm)
  bf16x8 kf[4];
#pragma unroll
  for (int c = 0; c < 4; ++c)
    kf[c] = *(const bf16x8*)(kk + (c * 16 + l16) * 32 + q4 * 8);

  // V B-fragments: vf[half][c2][j] = v[tok = half*32 + q4*8 + j][c2*16+l16]
  bf16x8 vf[2][2];
#pragma unroll
  for (int half = 0; half < 2; ++half)
#pragma unroll
    for (int c2 = 0; c2 < 2; ++c2)
#pragma unroll
      for (int j = 0; j < 8; ++j)
        vf[half][c2][j] = vv[(half * 32 + q4 * 8 + j) * 32 + c2 * 16 + l16];

  const f32x4 zero4 = {0.f, 0.f, 0.f, 0.f};

  for (int ts = 0; ts < 4; ++ts) {
    bf16x8 qf = *(const bf16x8*)(qq + (ts * 16 + l16) * 32 + q4 * 8);
    f32x4 s[4];
#pragma unroll
    for (int c = 0; c < 4; ++c)
      s[c] = __builtin_amdgcn_mfma_f32_16x16x32_bf16(qf, kf[c], zero4, 0, 0, 0);
#pragma unroll
    for (int c = 0; c < 4; ++c) {
      bf16x4 bv = *(const bf16x4*)(bmb + (ts * 4 + c) * 256 + lane * 4);
#pragma unroll
      for (int r = 0; r < 4; ++r) s[c][r] += (float)bv[r];
    }
#pragma unroll
    for (int r = 0; r < 4; ++r) {
      float m = fmaxf(fmaxf(s[0][r], s[1][r]), fmaxf(s[2][r], s[3][r]));
      m = fmaxf(m, __shfl_xor(m, 1));
      m = fmaxf(m, __shfl_xor(m, 2));
      m = fmaxf(m, __shfl_xor(m, 4));
      m = fmaxf(m, __shfl_xor(m, 8));
      float e0 = __expf(s[0][r] - m);
      float e1 = __expf(s[1][r] - m);
      float e2 = __expf(s[2][r] - m);
      float e3 = __expf(s[3][r] - m);
      float sm = e0 + e1 + e2 + e3;
      sm += __shfl_xor(sm, 1);
      sm += __shfl_xor(sm, 2);
      sm += __shfl_xor(sm, 4);
      sm += __shfl_xor(sm, 8);
      float inv = 1.0f / sm;
      int ir = q4 * 4 + r;
      P[wv][ir][l16] = (bf16)(e0 * inv);
      P[wv][ir][16 + l16] = (bf16)(e1 * inv);
      P[wv][ir][32 + l16] = (bf16)(e2 * inv);
      P[wv][ir][48 + l16] = (bf16)(e3 * inv);
    }
    __builtin_amdgcn_wave_barrier();   // pin ds_write < ds_read order
    bf16x8 p0 = *(const bf16x8*)&P[wv][l16][q4 * 8];
    bf16x8 p1 = *(const bf16x8*)&P[wv][l16][32 + q4 * 8];
    f32x4 o0 = __builtin_amdgcn_mfma_f32_16x16x32_bf16(p0, vf[0][0], zero4, 0, 0, 0);
    o0 = __builtin_amdgcn_mfma_f32_16x16x32_bf16(p1, vf[1][0], o0, 0, 0, 0);
    f32x4 o1 = __builtin_amdgcn_mfma_f32_16x16x32_bf16(p0, vf[0][1], zero4, 0, 0, 0);
    o1 = __builtin_amdgcn_mfma_f32_16x16x32_bf16(p1, vf[1][1], o1, 0, 0, 0);
    __builtin_amdgcn_wave_barrier();   // pin ds_read < next strip's ds_write
#pragma unroll
    for (int r = 0; r < 4; ++r) {
      int i = ts * 16 + q4 * 4 + r;
      if (i < 49) {
        bf16* dst = ab + (size_t)(w * 49 + i) * 384 + h * 32;
        dst[l16] = (bf16)o0[r];
        dst[16 + l16] = (bf16)o1[r];
      }
    }
  }
}

// --------------------------------------------------------------------------
// Proj GEMM [GTOK x 384, K=384] + pixel scatter (roll +3) to fp32 out.
// XCD swizzle, grid 2352.
// --------------------------------------------------------------------------
__global__ __launch_bounds__(256, 3) void k_proj(
    const bf16* __restrict__ ab, const bf16* __restrict__ wp,
    const float* __restrict__ bp, float* __restrict__ out) {
  __shared__ __align__(16) bf16 As[128 * 64];
  __shared__ __align__(16) bf16 Bs[128 * 64];

  int tid = threadIdx.x;
  int wv = tid >> 6, lane = tid & 63, l16 = lane & 15, q4 = lane >> 4;
  int wr = wv >> 1, wc = wv & 1;
  int bid = blockIdx.x;              // 2352
  int xcd = bid & 7, s = bid >> 3;
  int nb = s % 3, mt = s / 3;
  int m0 = (mt * 8 + xcd) * 128;
  int n0 = nb * 128;

  int srow = lane >> 3;
  int scg = lane & 7;

  f32x4 acc[4][4];
#pragma unroll
  for (int a = 0; a < 4; ++a)
#pragma unroll
    for (int b = 0; b < 4; ++b) acc[a][b] = (f32x4){0.f, 0.f, 0.f, 0.f};

  for (int k0 = 0; k0 < 384; k0 += 64) {
    __syncthreads();
#pragma unroll
    for (int st = 0; st < 4; ++st) {
      int row = (wv * 4 + st) * 8 + srow;
      int gc = (scg ^ (row & 7)) * 8;
      gld16(ab + (size_t)(m0 + row) * 384 + k0 + gc, As + (wv * 4 + st) * 512);
      gld16(wp + (size_t)(n0 + row) * 384 + k0 + gc, Bs + (wv * 4 + st) * 512);
    }
    __syncthreads();
#pragma unroll
    for (int kk = 0; kk < 2; ++kk) {
      bf16x8 af[4], bfr[4];
#pragma unroll
      for (int mi = 0; mi < 4; ++mi) {
        int m = wr * 64 + mi * 16 + l16;
        int g = kk * 4 + q4;
        af[mi] = *(const bf16x8*)(As + m * 64 + ((g ^ (m & 7)) * 8));
      }
#pragma unroll
      for (int ci = 0; ci < 4; ++ci) {
        int n = wc * 64 + ci * 16 + l16;
        int g = kk * 4 + q4;
        bfr[ci] = *(const bf16x8*)(Bs + n * 64 + ((g ^ (n & 7)) * 8));
      }
#pragma unroll
      for (int mi = 0; mi < 4; ++mi)
#pragma unroll
        for (int ci = 0; ci < 4; ++ci)
          acc[mi][ci] =
              __builtin_amdgcn_mfma_f32_16x16x32_bf16(af[mi], bfr[ci], acc[mi][ci], 0, 0, 0);
    }
  }

  float bias4[4]; int col4[4];
#pragma unroll
  for (int ci = 0; ci < 4; ++ci) {
    col4[ci] = n0 + wc * 64 + ci * 16 + l16;
    bias4[ci] = bp[col4[ci]];
  }
#pragma unroll
  for (int mi = 0; mi < 4; ++mi) {
#pragma unroll
    for (int r = 0; r < 4; ++r) {
      int mrow = m0 + wr * 64 + mi * 16 + q4 * 4 + r;
      int w = mrow / 49, t = mrow - w * 49;
      int b = w >> 6, wi = w & 63;
      int wy = wi >> 3, wx = wi & 7;
      int ty = t / 7, tx = t - ty * 7;
      int gy = wy * 7 + ty + 3; if (gy >= 56) gy -= 56;
      int gx = wx * 7 + tx + 3; if (gx >= 56) gx -= 56;
      float* orow = out + (size_t)((b * 56 + gy) * 56 + gx) * 384;
#pragma unroll
      for (int ci = 0; ci < 4; ++ci) orow[col4[ci]] = acc[mi][ci][r] + bias4[ci];
    }
  }
}

// --------------------------------------------------------------------------
extern "C" void kernel_launch(void* const* d_in, const int* in_sizes, int n_in,
                              void* d_out, int out_size, void* d_ws,
                              size_t ws_size, hipStream_t stream) {
  const float* x     = (const float*)d_in[0];
  const float* wqkv  = (const float*)d_in[1];
  const float* bqkv  = (const float*)d_in[2];
  const float* wproj = (const float*)d_in[3];
  const float* bproj = (const float*)d_in[4];
  const float* table = (const float*)d_in[5];
  float* out = (float*)d_out;

  char* ws = (char*)d_ws;
  bf16* qb  = (bf16*)(ws + QB_OFF);
  bf16* kb  = (bf16*)(ws + KB_OFF);
  bf16* vb  = (bf16*)(ws + VB_OFF);
  bf16* xg  = (bf16*)(ws + XG_OFF);
  bf16* ab  = (bf16*)(ws + XG_OFF);   // overlays xg (dead after k_qkv)
  bf16* bmb = (bf16*)(ws + BM_OFF);
  bf16* wqg = (bf16*)(ws + WQ_OFF);
  bf16* wpg = (bf16*)(ws + WP_OFF);

  k_prep<<<dim3(31392), dim3(256), 0, stream>>>(x, wqkv, wproj, table,
                                                xg, wqg, wpg, bmb);
  k_qkv<<<dim3(7056), dim3(256), 0, stream>>>(xg, wqg, bqkv, qb, kb, vb);
  k_attn<<<dim3(6144), dim3(256), 0, stream>>>(qb, kb, vb, bmb, ab);
  k_proj<<<dim3(2352), dim3(256), 0, stream>>>(ab, wpg, bproj, out);
}